// Round 1
// baseline (285.114 us; speedup 1.0000x reference)
//
#include <hip/hip_runtime.h>
#include <stdint.h>

#define T_SEQ 2048
#define CEMB  1024
#define NHEAD 16
#define HS    64
#define NBH   32     // B*H
#define MROWS 4096   // B*T

typedef unsigned short u16;
typedef __attribute__((ext_vector_type(8))) __bf16 bf16x8;
typedef __attribute__((ext_vector_type(4))) float  f32x4;

__device__ __forceinline__ u16 f2bf(float f) {
  union { float f; uint32_t u; } c; c.f = f;
  return (u16)((c.u + 0x7FFFu + ((c.u >> 16) & 1u)) >> 16);
}

__device__ __forceinline__ bf16x8 ld8(const u16* p) {
  return *(const bf16x8*)(const void*)p;
}

#define ASYNC_CP16(gsrc, ldst)                                                  \
  __builtin_amdgcn_global_load_lds(                                             \
      (const __attribute__((address_space(1))) void*)(gsrc),                    \
      (__attribute__((address_space(3))) void*)(ldst), 16, 0, 0)

// ---------------- convert x -> bf16 ----------------
__global__ __launch_bounds__(256) void cvt_x_kernel(const float* __restrict__ x,
                                                    u16* __restrict__ xb) {
  size_t i = ((size_t)blockIdx.x * 256 + threadIdx.x) * 4;
  float4 v = *(const float4*)(x + i);
  ushort4 o;
  o.x = f2bf(v.x); o.y = f2bf(v.y); o.z = f2bf(v.z); o.w = f2bf(v.w);
  *(ushort4*)(xb + i) = o;
}

// ------- convert W[h][c][d] -> Wt[w][n=h*64+d][c] bf16 (B^T layout) -------
__global__ __launch_bounds__(256) void cvt_w_kernel(const float* __restrict__ Wq,
                                                    const float* __restrict__ Wk,
                                                    const float* __restrict__ Wv,
                                                    u16* __restrict__ Wt) {
  int idx = blockIdx.x * 256 + threadIdx.x;   // over 3*1024*1024
  int w = idx >> 20;
  int n = (idx >> 10) & 1023;
  int c = idx & 1023;
  const float* W = (w == 0) ? Wq : (w == 1) ? Wk : Wv;
  Wt[idx] = f2bf(W[(size_t)((n >> 6) * CEMB + c) * HS + (n & 63)]);
}

// ---------------- projection GEMM: [4096x1024] x [1024x1024]^T ----------------
// 128x128 tile, BK=64, 4 waves, global_load_lds staging, XOR-swizzled LDS.
// Output written as bf16 [bh][t][d].
#define BM 128
#define BN 128
#define BK 64

__global__ __launch_bounds__(256, 2) void proj_gemm(const u16* __restrict__ xb,
                                                    const u16* __restrict__ Wt,
                                                    u16* __restrict__ Qb,
                                                    u16* __restrict__ Kb,
                                                    u16* __restrict__ Vb) {
  __shared__ u16 As[BM * BK];   // 16 KB, rows of 128 B, granules XOR-swizzled
  __shared__ u16 Bs[BN * BK];   // 16 KB
  int z = blockIdx.z;
  const u16* Wz = Wt + (size_t)z * (1024 * 1024);
  u16* outp = (z == 0) ? Qb : (z == 1) ? Kb : Vb;
  int tile_m = blockIdx.x * BM;
  int tile_n = blockIdx.y * BN;
  int tid  = threadIdx.x;
  int lane = tid & 63;
  int wave = tid >> 6;
  int wr = wave >> 1, wc = wave & 1;
  int l15 = lane & 15, lg = lane >> 4;

  f32x4 acc[4][4] = {};

  for (int k0 = 0; k0 < CEMB; k0 += BK) {
    // stage A and B tiles: linear LDS dest, inverse-swizzled global source
#pragma unroll
    for (int j = 0; j < 4; ++j) {
      int off = j * 4096 + tid * 16;        // linear byte offset in tile
      int row = off >> 7;                   // 128 B per row
      int g   = (off >> 4) & 7;             // physical 16B granule in row
      int col = ((g ^ (row & 7)) << 3);     // logical elem col this slot holds
      const u16* srcA = xb + (size_t)(tile_m + row) * CEMB + k0 + col;
      ASYNC_CP16(srcA, (char*)As + j * 4096 + wave * 1024);
      const u16* srcB = Wz + (size_t)(tile_n + row) * CEMB + k0 + col;
      ASYNC_CP16(srcB, (char*)Bs + j * 4096 + wave * 1024);
    }
    __syncthreads();

    bf16x8 af[2][4], bfr[2][4];
#pragma unroll
    for (int kk = 0; kk < 2; ++kk) {
#pragma unroll
      for (int m = 0; m < 4; ++m) {
        int row = wr * 64 + m * 16 + l15;
        int g   = kk * 4 + lg;
        af[kk][m] = *(const bf16x8*)(const void*)((const char*)As + row * 128 +
                                                  ((g ^ (row & 7)) << 4));
      }
#pragma unroll
      for (int n = 0; n < 4; ++n) {
        int row = wc * 64 + n * 16 + l15;
        int g   = kk * 4 + lg;
        bfr[kk][n] = *(const bf16x8*)(const void*)((const char*)Bs + row * 128 +
                                                   ((g ^ (row & 7)) << 4));
      }
    }
#pragma unroll
    for (int kk = 0; kk < 2; ++kk)
#pragma unroll
      for (int m = 0; m < 4; ++m)
#pragma unroll
        for (int n = 0; n < 4; ++n)
          acc[m][n] = __builtin_amdgcn_mfma_f32_16x16x32_bf16(af[kk][m], bfr[kk][n],
                                                              acc[m][n], 0, 0, 0);
    __syncthreads();
  }

  // epilogue: C[row][col] -> out[bh][t][d] bf16
#pragma unroll
  for (int m = 0; m < 4; ++m)
#pragma unroll
    for (int n = 0; n < 4; ++n)
#pragma unroll
      for (int i = 0; i < 4; ++i) {
        int row = tile_m + wr * 64 + m * 16 + lg * 4 + i;  // b*T + t
        int col = tile_n + wc * 64 + n * 16 + l15;         // h*64 + d
        int b = row >> 11, t = row & 2047;
        int h = col >> 6,  d = col & 63;
        outp[(size_t)((b << 4) + h) * (T_SEQ * HS) + (size_t)t * HS + d] =
            f2bf(acc[m][n][i]);
      }
}

// ---------------- V [bh][t][d] -> Vt [bh][d][t] ----------------
__global__ __launch_bounds__(256) void transpose_v_kernel(const u16* __restrict__ Vb,
                                                          u16* __restrict__ Vt) {
  __shared__ u16 tile[64][72];
  int bh = blockIdx.y;
  int t0 = blockIdx.x * 64;
  int tid = threadIdx.x;
  int r = tid >> 3, c8 = (tid & 7) * 8;
  const u16* src = Vb + ((size_t)bh * T_SEQ + t0) * HS;
#pragma unroll
  for (int p = 0; p < 2; ++p) {
    int rr = r + p * 32;
    bf16x8 v = ld8(src + rr * HS + c8);
#pragma unroll
    for (int j = 0; j < 8; ++j) tile[rr][c8 + j] = ((const u16*)&v)[j];
  }
  __syncthreads();
  u16* dst = Vt + (size_t)bh * HS * T_SEQ + t0;
#pragma unroll
  for (int p = 0; p < 2; ++p) {
    int d = r + p * 32;
    u16 tmp[8] __attribute__((aligned(16)));
#pragma unroll
    for (int j = 0; j < 8; ++j) tmp[j] = tile[c8 + j][d];
    *(bf16x8*)(void*)(dst + (size_t)d * T_SEQ + c8) = *(const bf16x8*)(const void*)tmp;
  }
}

// ---------------- causal flash attention ----------------
// Block: 4 independent waves, each owns 16 q rows. K/V read straight from
// global (L2-resident per bh). P routed through swizzled per-wave LDS.
__global__ __launch_bounds__(256, 2) void attn_kernel(const u16* __restrict__ Qb,
                                                      const u16* __restrict__ Kb,
                                                      const u16* __restrict__ Vt,
                                                      float* __restrict__ out) {
  __shared__ char Plds[4][2048];   // per wave: 16 rows x 128 B (swizzled)
  int bh = blockIdx.y;
  int qb = blockIdx.x;             // 0..31
  int lane = threadIdx.x & 63;
  int wave = threadIdx.x >> 6;
  int l15 = lane & 15, lg = lane >> 4;
  int qw = qb * 64 + wave * 16;    // first q row of this wave

  const u16* Qh = Qb + (size_t)bh * T_SEQ * HS;
  const u16* Kh = Kb + (size_t)bh * T_SEQ * HS;
  const u16* Vh = Vt + (size_t)bh * HS * T_SEQ;

  bf16x8 qf[2];
  qf[0] = ld8(Qh + (size_t)(qw + l15) * HS + lg * 8);
  qf[1] = ld8(Qh + (size_t)(qw + l15) * HS + 32 + lg * 8);

  f32x4 ao[4] = {};
  float mrow[4] = {-1e30f, -1e30f, -1e30f, -1e30f};
  float lrow[4] = {};
  const float sc = 0.03125f * 1.44269504f;   // log2(e) / sqrt(C)

  char* pb = Plds[wave];
  int lastt = qb;                  // (qw+15)>>6 == qb for all 4 waves
  for (int t = 0; t <= lastt; ++t) {
    // ---- S = Q K^T over 64 kv cols ----
    f32x4 sf[4];
#pragma unroll
    for (int n = 0; n < 4; ++n) {
      const u16* kp = Kh + (size_t)(t * 64 + n * 16 + l15) * HS + lg * 8;
      bf16x8 kf0 = ld8(kp);
      bf16x8 kf1 = ld8(kp + 32);
      f32x4 s = {};
      s = __builtin_amdgcn_mfma_f32_16x16x32_bf16(qf[0], kf0, s, 0, 0, 0);
      s = __builtin_amdgcn_mfma_f32_16x16x32_bf16(qf[1], kf1, s, 0, 0, 0);
      sf[n] = s;
    }
    // scale to log2 domain + causal mask (only last tile crosses diagonal)
    bool need_mask = (t == lastt);
#pragma unroll
    for (int n = 0; n < 4; ++n)
#pragma unroll
      for (int i = 0; i < 4; ++i) {
        float v = sf[n][i] * sc;
        if (need_mask) {
          int colg = t * 64 + n * 16 + l15;
          int rowg = qw + lg * 4 + i;
          if (colg > rowg) v = -1e30f;
        }
        sf[n][i] = v;
      }
    // ---- online softmax (rows live across 16 lanes, per reg i) ----
    float pscale[4];
#pragma unroll
    for (int i = 0; i < 4; ++i) {
      float vmax = fmaxf(fmaxf(sf[0][i], sf[1][i]), fmaxf(sf[2][i], sf[3][i]));
      vmax = fmaxf(vmax, __shfl_xor(vmax, 1));
      vmax = fmaxf(vmax, __shfl_xor(vmax, 2));
      vmax = fmaxf(vmax, __shfl_xor(vmax, 4));
      vmax = fmaxf(vmax, __shfl_xor(vmax, 8));
      float mnew = fmaxf(mrow[i], vmax);
      pscale[i] = exp2f(mrow[i] - mnew);
      mrow[i] = mnew;
      float rsum = 0.f;
#pragma unroll
      for (int n = 0; n < 4; ++n) {
        float p = exp2f(sf[n][i] - mnew);
        sf[n][i] = p;
        rsum += p;
      }
      rsum += __shfl_xor(rsum, 1);
      rsum += __shfl_xor(rsum, 2);
      rsum += __shfl_xor(rsum, 4);
      rsum += __shfl_xor(rsum, 8);
      lrow[i] = lrow[i] * pscale[i] + rsum;
    }
#pragma unroll
    for (int nd = 0; nd < 4; ++nd)
#pragma unroll
      for (int i = 0; i < 4; ++i) ao[nd][i] *= pscale[i];

    // ---- P (D-layout) -> LDS (swizzled) -> A-frags ----
#pragma unroll
    for (int n = 0; n < 4; ++n)
#pragma unroll
      for (int i = 0; i < 4; ++i) {
        int row = lg * 4 + i;
        int col = n * 16 + l15;
        int g = col >> 3;
        *(u16*)(pb + row * 128 + ((g ^ (row & 7)) << 4) + (col & 7) * 2) =
            f2bf(sf[n][i]);
      }
    bf16x8 pf[2];
#pragma unroll
    for (int kk = 0; kk < 2; ++kk) {
      int row = l15;
      int g = kk * 4 + lg;
      pf[kk] = *(const bf16x8*)(const void*)(pb + row * 128 + ((g ^ (row & 7)) << 4));
    }
    // ---- O += P V  (B-operand = Vt rows, contiguous 16B) ----
#pragma unroll
    for (int nd = 0; nd < 4; ++nd) {
      const u16* vp = Vh + (size_t)(nd * 16 + l15) * T_SEQ + t * 64 + lg * 8;
      bf16x8 vf0 = ld8(vp);
      bf16x8 vf1 = ld8(vp + 32);
      ao[nd] = __builtin_amdgcn_mfma_f32_16x16x32_bf16(pf[0], vf0, ao[nd], 0, 0, 0);
      ao[nd] = __builtin_amdgcn_mfma_f32_16x16x32_bf16(pf[1], vf1, ao[nd], 0, 0, 0);
    }
  }
  // ---- epilogue: out[b][t][h*64+d] f32 ----
  int bb = bh >> 4, hh = bh & 15;
#pragma unroll
  for (int i = 0; i < 4; ++i) {
    float inv = 1.0f / lrow[i];
    int trow = qw + lg * 4 + i;
    float* op = out + ((size_t)bb * T_SEQ + trow) * CEMB + hh * HS;
#pragma unroll
    for (int nd = 0; nd < 4; ++nd) op[nd * 16 + l15] = ao[nd][i] * inv;
  }
}

extern "C" void kernel_launch(void* const* d_in, const int* in_sizes, int n_in,
                              void* d_out, int out_size, void* d_ws, size_t ws_size,
                              hipStream_t stream) {
  const float* x  = (const float*)d_in[0];
  const float* Wq = (const float*)d_in[1];
  const float* Wk = (const float*)d_in[2];
  const float* Wv = (const float*)d_in[3];
  float* out = (float*)d_out;
  char* ws = (char*)d_ws;

  // workspace layout (38 MB):
  u16* xb = (u16*)ws;                      // 8 MB  [4096][1024] bf16; reused as Vt
  u16* Wt = (u16*)(ws + (8u << 20));       // 6 MB  [3][1024][1024] bf16
  u16* Qb = (u16*)(ws + (14u << 20));      // 8 MB  [bh][t][d] bf16
  u16* Kb = (u16*)(ws + (22u << 20));      // 8 MB
  u16* Vb = (u16*)(ws + (30u << 20));      // 8 MB
  u16* Vt = xb;                            // xb dead after proj_gemm

  cvt_x_kernel<<<4096, 256, 0, stream>>>(x, xb);
  cvt_w_kernel<<<12288, 256, 0, stream>>>(Wq, Wk, Wv, Wt);
  proj_gemm<<<dim3(32, 8, 3), 256, 0, stream>>>(xb, Wt, Qb, Kb, Vb);
  transpose_v_kernel<<<dim3(32, 32), 256, 0, stream>>>(Vb, Vt);
  attn_kernel<<<dim3(32, 32), 256, 0, stream>>>(Qb, Kb, Vt, out);
}

// Round 2
// 156.577 us; speedup vs baseline: 1.8209x; 1.8209x over previous
//
#include <hip/hip_runtime.h>
#include <stdint.h>

#define T_SEQ 2048
#define CEMB  1024
#define NHEAD 16
#define HS    64
#define NBH   32     // B*H
#define MROWS 4096   // B*T

typedef unsigned short u16;
typedef __attribute__((ext_vector_type(8))) __bf16 bf16x8;
typedef __attribute__((ext_vector_type(4))) float  f32x4;

__device__ __forceinline__ u16 f2bf(float f) {
  union { float f; uint32_t u; } c; c.f = f;
  return (u16)((c.u + 0x7FFFu + ((c.u >> 16) & 1u)) >> 16);
}

__device__ __forceinline__ bf16x8 ld8(const u16* p) {
  return *(const bf16x8*)(const void*)p;
}

#define ASYNC_CP16(gsrc, ldst)                                                  \
  __builtin_amdgcn_global_load_lds(                                             \
      (const __attribute__((address_space(1))) void*)(gsrc),                    \
      (__attribute__((address_space(3))) void*)(ldst), 16, 0, 0)

// ---------------- convert x -> bf16 ----------------
__global__ __launch_bounds__(256) void cvt_x_kernel(const float* __restrict__ x,
                                                    u16* __restrict__ xb) {
  size_t i = ((size_t)blockIdx.x * 256 + threadIdx.x) * 4;
  float4 v = *(const float4*)(x + i);
  ushort4 o;
  o.x = f2bf(v.x); o.y = f2bf(v.y); o.z = f2bf(v.z); o.w = f2bf(v.w);
  *(ushort4*)(xb + i) = o;
}

// ------- convert W[h][c][d] -> Wt[w][n=h*64+d][c] bf16 (B^T layout) -------
// LDS-tiled transpose: coalesced float4 reads, coalesced ushort4 writes.
__global__ __launch_bounds__(256) void cvt_w_kernel(const float* __restrict__ Wq,
                                                    const float* __restrict__ Wk,
                                                    const float* __restrict__ Wv,
                                                    u16* __restrict__ Wt) {
  __shared__ float tile[64][65];
  int w = blockIdx.z, h = blockIdx.y;
  int c0 = blockIdx.x * 64;
  const float* W = ((w == 0) ? Wq : (w == 1) ? Wk : Wv) + (size_t)h * CEMB * HS;
  int tid = threadIdx.x;
  int r = tid >> 4;            // 0..15
  int d4 = (tid & 15) * 4;
#pragma unroll
  for (int p = 0; p < 4; ++p) {
    int row = p * 16 + r;      // c-local
    float4 v = *(const float4*)(W + (size_t)(c0 + row) * HS + d4);
    tile[row][d4] = v.x; tile[row][d4 + 1] = v.y;
    tile[row][d4 + 2] = v.z; tile[row][d4 + 3] = v.w;
  }
  __syncthreads();
  u16* dst = Wt + ((size_t)w << 20);
#pragma unroll
  for (int p = 0; p < 4; ++p) {
    int d = p * 16 + r;
    ushort4 o;
    o.x = f2bf(tile[d4][d]);     o.y = f2bf(tile[d4 + 1][d]);
    o.z = f2bf(tile[d4 + 2][d]); o.w = f2bf(tile[d4 + 3][d]);
    *(ushort4*)(dst + (size_t)(h * 64 + d) * CEMB + c0 + d4) = o;
  }
}

// ---------------- projection GEMM: [4096x1024] x [1024x1024]^T ----------------
#define BM 128
#define BN 128
#define BK 64

__global__ __launch_bounds__(256, 2) void proj_gemm(const u16* __restrict__ xb,
                                                    const u16* __restrict__ Wt,
                                                    u16* __restrict__ Qb,
                                                    u16* __restrict__ Kb,
                                                    u16* __restrict__ Vb) {
  __shared__ u16 As[BM * BK];   // 16 KB
  __shared__ u16 Bs[BN * BK];   // 16 KB
  int z = blockIdx.z;
  const u16* Wz = Wt + (size_t)z * (1024 * 1024);
  u16* outp = (z == 0) ? Qb : (z == 1) ? Kb : Vb;
  int tile_m = blockIdx.x * BM;
  int tile_n = blockIdx.y * BN;
  int tid  = threadIdx.x;
  int lane = tid & 63;
  int wave = tid >> 6;
  int wr = wave >> 1, wc = wave & 1;
  int l15 = lane & 15, lg = lane >> 4;

  f32x4 acc[4][4] = {};

  for (int k0 = 0; k0 < CEMB; k0 += BK) {
#pragma unroll
    for (int j = 0; j < 4; ++j) {
      int off = j * 4096 + tid * 16;
      int row = off >> 7;
      int g   = (off >> 4) & 7;
      int col = ((g ^ (row & 7)) << 3);
      const u16* srcA = xb + (size_t)(tile_m + row) * CEMB + k0 + col;
      ASYNC_CP16(srcA, (char*)As + j * 4096 + wave * 1024);
      const u16* srcB = Wz + (size_t)(tile_n + row) * CEMB + k0 + col;
      ASYNC_CP16(srcB, (char*)Bs + j * 4096 + wave * 1024);
    }
    __syncthreads();

    bf16x8 af[2][4], bfr[2][4];
#pragma unroll
    for (int kk = 0; kk < 2; ++kk) {
#pragma unroll
      for (int m = 0; m < 4; ++m) {
        int row = wr * 64 + m * 16 + l15;
        int g   = kk * 4 + lg;
        af[kk][m] = *(const bf16x8*)(const void*)((const char*)As + row * 128 +
                                                  ((g ^ (row & 7)) << 4));
      }
#pragma unroll
      for (int n = 0; n < 4; ++n) {
        int row = wc * 64 + n * 16 + l15;
        int g   = kk * 4 + lg;
        bfr[kk][n] = *(const bf16x8*)(const void*)((const char*)Bs + row * 128 +
                                                   ((g ^ (row & 7)) << 4));
      }
    }
#pragma unroll
    for (int kk = 0; kk < 2; ++kk)
#pragma unroll
      for (int m = 0; m < 4; ++m)
#pragma unroll
        for (int n = 0; n < 4; ++n)
          acc[m][n] = __builtin_amdgcn_mfma_f32_16x16x32_bf16(af[kk][m], bfr[kk][n],
                                                              acc[m][n], 0, 0, 0);
    __syncthreads();
  }

#pragma unroll
  for (int m = 0; m < 4; ++m)
#pragma unroll
    for (int n = 0; n < 4; ++n)
#pragma unroll
      for (int i = 0; i < 4; ++i) {
        int row = tile_m + wr * 64 + m * 16 + lg * 4 + i;  // b*T + t
        int col = tile_n + wc * 64 + n * 16 + l15;         // h*64 + d
        int b = row >> 11, t = row & 2047;
        int h = col >> 6,  d = col & 63;
        outp[(size_t)((b << 4) + h) * (T_SEQ * HS) + (size_t)t * HS + d] =
            f2bf(acc[m][n][i]);
      }
}

// ---------------- V [bh][t][d] -> Vt [bh][d][t] ----------------
__global__ __launch_bounds__(256) void transpose_v_kernel(const u16* __restrict__ Vb,
                                                          u16* __restrict__ Vt) {
  __shared__ u16 tile[64][72];
  int bh = blockIdx.y;
  int t0 = blockIdx.x * 64;
  int tid = threadIdx.x;
  int r = tid >> 3, c8 = (tid & 7) * 8;
  const u16* src = Vb + ((size_t)bh * T_SEQ + t0) * HS;
#pragma unroll
  for (int p = 0; p < 2; ++p) {
    int rr = r + p * 32;
    bf16x8 v = ld8(src + rr * HS + c8);
#pragma unroll
    for (int j = 0; j < 8; ++j) tile[rr][c8 + j] = ((const u16*)&v)[j];
  }
  __syncthreads();
  u16* dst = Vt + (size_t)bh * HS * T_SEQ + t0;
#pragma unroll
  for (int p = 0; p < 2; ++p) {
    int d = r + p * 32;
    u16 tmp[8] __attribute__((aligned(16)));
#pragma unroll
    for (int j = 0; j < 8; ++j) tmp[j] = tile[c8 + j][d];
    *(bf16x8*)(void*)(dst + (size_t)d * T_SEQ + c8) = *(const bf16x8*)(const void*)tmp;
  }
}

// ---------------- causal flash attention v2 ----------------
// Block: 4 waves x 32 q-rows = 128 q-rows. K/V tiles double-buffered in LDS
// (shared by all waves, staged via global_load_lds w=16, XOR-swizzled).
// 2-phase pipeline: issue STAGE(t+1) before computing tile t.
__global__ __launch_bounds__(256, 2) void attn_kernel(const u16* __restrict__ Qb,
                                                      const u16* __restrict__ Kb,
                                                      const u16* __restrict__ Vt,
                                                      float* __restrict__ out) {
  __shared__ u16 Ks[2][4096];   // 2 x 64 kv-rows x 64 d  (8 KB each)
  __shared__ u16 Vs[2][4096];   // 2 x 64 d-rows x 64 t
  __shared__ char Plds[4][4096]; // per wave: 32 rows x 128 B (swizzled)

  int bh = blockIdx.x;
  int y  = blockIdx.y;
  int qb = (y < 8) ? y : 23 - y;   // pair-balanced: work(l) + work(l+256) = const
  int tid = threadIdx.x;
  int lane = tid & 63, wave = tid >> 6;
  int l15 = lane & 15, lg = lane >> 4;
  int qw = qb * 128 + wave * 32;   // first q row of this wave

  const u16* Qh = Qb + (size_t)bh * T_SEQ * HS;
  const u16* Kh = Kb + (size_t)bh * T_SEQ * HS;
  const u16* Vh = Vt + (size_t)bh * HS * T_SEQ;

#define STAGE(tt, bb) do {                                                      \
    _Pragma("unroll")                                                           \
    for (int is = 0; is < 2; ++is) {                                            \
      int off_ = is * 4096 + tid * 16;                                          \
      int row_ = off_ >> 7;                                                     \
      int col_ = ((((off_ >> 4) & 7) ^ (row_ & 7)) << 3);                       \
      const u16* srcK_ = Kh + (size_t)((tt) * 64 + row_) * HS + col_;           \
      ASYNC_CP16(srcK_, (char*)Ks[bb] + is * 4096 + wave * 1024);               \
      const u16* srcV_ = Vh + (size_t)row_ * T_SEQ + (tt) * 64 + col_;          \
      ASYNC_CP16(srcV_, (char*)Vs[bb] + is * 4096 + wave * 1024);               \
    }                                                                           \
  } while (0)

  // Q fragments (2 m-frags x 2 k-halves)
  bf16x8 qf[2][2];
#pragma unroll
  for (int m = 0; m < 2; ++m)
#pragma unroll
    for (int kk = 0; kk < 2; ++kk)
      qf[m][kk] = ld8(Qh + (size_t)(qw + m * 16 + l15) * HS + kk * 32 + lg * 8);

  f32x4 ao[2][4] = {};
  float mrow[2][4], lrow[2][4];
#pragma unroll
  for (int m = 0; m < 2; ++m)
#pragma unroll
    for (int i = 0; i < 4; ++i) { mrow[m][i] = -1e30f; lrow[m][i] = 0.f; }

  const float sc = 0.03125f * 1.44269504f;   // log2(e) / sqrt(C)
  char* pb = Plds[wave];
  int lastt = (qw + 31) >> 6;
  int maxT  = 2 * qb + 1;

  STAGE(0, 0);
  __syncthreads();

  for (int t = 0; t <= maxT; ++t) {
    int b = t & 1;
    if (t < maxT) STAGE(t + 1, b ^ 1);

    if (t <= lastt) {
      // ---- K frags from LDS ----
      bf16x8 kf[2][4];
#pragma unroll
      for (int kk = 0; kk < 2; ++kk)
#pragma unroll
        for (int n = 0; n < 4; ++n) {
          int row = n * 16 + l15;
          int g = kk * 4 + lg;
          kf[kk][n] = *(const bf16x8*)(const void*)((const char*)Ks[b] + row * 128 +
                                                    ((g ^ (row & 7)) << 4));
        }
      // ---- S = Q K^T ----
      f32x4 sf[2][4];
#pragma unroll
      for (int m = 0; m < 2; ++m)
#pragma unroll
        for (int n = 0; n < 4; ++n) {
          f32x4 s = {};
          s = __builtin_amdgcn_mfma_f32_16x16x32_bf16(qf[m][0], kf[0][n], s, 0, 0, 0);
          s = __builtin_amdgcn_mfma_f32_16x16x32_bf16(qf[m][1], kf[1][n], s, 0, 0, 0);
          sf[m][n] = s;
        }
      // ---- scale + causal mask ----
      bool nm = (t == lastt);
#pragma unroll
      for (int m = 0; m < 2; ++m)
#pragma unroll
        for (int n = 0; n < 4; ++n)
#pragma unroll
          for (int i = 0; i < 4; ++i) {
            float v = sf[m][n][i] * sc;
            if (nm) {
              int colg = t * 64 + n * 16 + l15;
              int rowg = qw + m * 16 + lg * 4 + i;
              if (colg > rowg) v = -1e30f;
            }
            sf[m][n][i] = v;
          }
      // ---- online softmax ----
      float pscale[2][4];
#pragma unroll
      for (int m = 0; m < 2; ++m)
#pragma unroll
        for (int i = 0; i < 4; ++i) {
          float vmax = fmaxf(fmaxf(sf[m][0][i], sf[m][1][i]),
                             fmaxf(sf[m][2][i], sf[m][3][i]));
          vmax = fmaxf(vmax, __shfl_xor(vmax, 1));
          vmax = fmaxf(vmax, __shfl_xor(vmax, 2));
          vmax = fmaxf(vmax, __shfl_xor(vmax, 4));
          vmax = fmaxf(vmax, __shfl_xor(vmax, 8));
          float mnew = fmaxf(mrow[m][i], vmax);
          float ps = exp2f(mrow[m][i] - mnew);
          pscale[m][i] = ps;
          mrow[m][i] = mnew;
          float rsum = 0.f;
#pragma unroll
          for (int n = 0; n < 4; ++n) {
            float p = exp2f(sf[m][n][i] - mnew);
            sf[m][n][i] = p;
            rsum += p;
          }
          rsum += __shfl_xor(rsum, 1);
          rsum += __shfl_xor(rsum, 2);
          rsum += __shfl_xor(rsum, 4);
          rsum += __shfl_xor(rsum, 8);
          lrow[m][i] = lrow[m][i] * ps + rsum;
        }
#pragma unroll
      for (int m = 0; m < 2; ++m)
#pragma unroll
        for (int nd = 0; nd < 4; ++nd)
#pragma unroll
          for (int i = 0; i < 4; ++i) ao[m][nd][i] *= pscale[m][i];

      // ---- P (D-layout) -> per-wave LDS (swizzled) -> A-frags ----
#pragma unroll
      for (int m = 0; m < 2; ++m)
#pragma unroll
        for (int n = 0; n < 4; ++n)
#pragma unroll
          for (int i = 0; i < 4; ++i) {
            int row = m * 16 + lg * 4 + i;
            int col = n * 16 + l15;
            int g = col >> 3;
            *(u16*)(pb + row * 128 + ((g ^ (row & 7)) << 4) + (col & 7) * 2) =
                f2bf(sf[m][n][i]);
          }
      bf16x8 pf[2][2];
#pragma unroll
      for (int m = 0; m < 2; ++m)
#pragma unroll
        for (int kk = 0; kk < 2; ++kk) {
          int row = m * 16 + l15;
          int g = kk * 4 + lg;
          pf[m][kk] = *(const bf16x8*)(const void*)(pb + row * 128 +
                                                    ((g ^ (row & 7)) << 4));
        }
      // ---- O += P V ----
      bf16x8 vf[2][4];
#pragma unroll
      for (int kk = 0; kk < 2; ++kk)
#pragma unroll
        for (int nd = 0; nd < 4; ++nd) {
          int row = nd * 16 + l15;
          int g = kk * 4 + lg;
          vf[kk][nd] = *(const bf16x8*)(const void*)((const char*)Vs[b] + row * 128 +
                                                     ((g ^ (row & 7)) << 4));
        }
#pragma unroll
      for (int m = 0; m < 2; ++m)
#pragma unroll
        for (int nd = 0; nd < 4; ++nd) {
          ao[m][nd] = __builtin_amdgcn_mfma_f32_16x16x32_bf16(pf[m][0], vf[0][nd],
                                                              ao[m][nd], 0, 0, 0);
          ao[m][nd] = __builtin_amdgcn_mfma_f32_16x16x32_bf16(pf[m][1], vf[1][nd],
                                                              ao[m][nd], 0, 0, 0);
        }
    }
    __syncthreads();
  }

  // ---- epilogue: out[b][t][h*64+d] f32 ----
  int bb = bh >> 4, hh = bh & 15;
#pragma unroll
  for (int m = 0; m < 2; ++m)
#pragma unroll
    for (int i = 0; i < 4; ++i) {
      float inv = 1.0f / lrow[m][i];
      int trow = qw + m * 16 + lg * 4 + i;
      float* op = out + ((size_t)bb * T_SEQ + trow) * CEMB + hh * HS;
#pragma unroll
      for (int nd = 0; nd < 4; ++nd) op[nd * 16 + l15] = ao[m][nd][i] * inv;
    }
#undef STAGE
}

extern "C" void kernel_launch(void* const* d_in, const int* in_sizes, int n_in,
                              void* d_out, int out_size, void* d_ws, size_t ws_size,
                              hipStream_t stream) {
  const float* x  = (const float*)d_in[0];
  const float* Wq = (const float*)d_in[1];
  const float* Wk = (const float*)d_in[2];
  const float* Wv = (const float*)d_in[3];
  float* out = (float*)d_out;
  char* ws = (char*)d_ws;

  u16* xb = (u16*)ws;                      // 8 MB  [4096][1024] bf16; reused as Vt
  u16* Wt = (u16*)(ws + (8u << 20));       // 6 MB  [3][1024][1024] bf16
  u16* Qb = (u16*)(ws + (14u << 20));      // 8 MB  [bh][t][d] bf16
  u16* Kb = (u16*)(ws + (22u << 20));      // 8 MB
  u16* Vb = (u16*)(ws + (30u << 20));      // 8 MB
  u16* Vt = xb;                            // xb dead after proj_gemm

  cvt_x_kernel<<<4096, 256, 0, stream>>>(x, xb);
  cvt_w_kernel<<<dim3(16, 16, 3), 256, 0, stream>>>(Wq, Wk, Wv, Wt);
  proj_gemm<<<dim3(32, 8, 3), 256, 0, stream>>>(xb, Wt, Qb, Kb, Vb);
  transpose_v_kernel<<<dim3(32, 32), 256, 0, stream>>>(Vb, Vt);
  attn_kernel<<<dim3(32, 16), 256, 0, stream>>>(Qb, Kb, Vt, out);
}

// Round 3
// 112.350 us; speedup vs baseline: 2.5377x; 1.3937x over previous
//
#include <hip/hip_runtime.h>
#include <stdint.h>

#define T_SEQ 2048
#define CEMB  1024
#define NHEAD 16
#define HS    64
#define NBH   32     // B*H
#define MROWS 4096   // B*T

typedef unsigned short u16;
typedef __attribute__((ext_vector_type(8)))  __bf16 bf16x8;
typedef __attribute__((ext_vector_type(4)))  float  f32x4;
typedef __attribute__((ext_vector_type(16))) float  f32x16;

__device__ __forceinline__ u16 f2bf(float f) {
  union { float f; uint32_t u; } c; c.f = f;
  return (u16)((c.u + 0x7FFFu + ((c.u >> 16) & 1u)) >> 16);
}

// pack two f32 -> u32 of 2 bf16 (a in low half), round-half-up via v_perm_b32
__device__ __forceinline__ uint32_t pkbf(float a, float b) {
  return __builtin_amdgcn_perm(__float_as_uint(b) + 0x8000u,
                               __float_as_uint(a) + 0x8000u, 0x07060302u);
}

__device__ __forceinline__ bf16x8 ld8(const u16* p) {
  return *(const bf16x8*)(const void*)p;
}

#define ASYNC_CP16(gsrc, ldst)                                                  \
  __builtin_amdgcn_global_load_lds(                                             \
      (const __attribute__((address_space(1))) void*)(gsrc),                    \
      (__attribute__((address_space(3))) void*)(ldst), 16, 0, 0)

// ---------------- convert x -> bf16 ----------------
__global__ __launch_bounds__(256) void cvt_x_kernel(const float* __restrict__ x,
                                                    u16* __restrict__ xb) {
  size_t i = ((size_t)blockIdx.x * 256 + threadIdx.x) * 4;
  float4 v = *(const float4*)(x + i);
  ushort4 o;
  o.x = f2bf(v.x); o.y = f2bf(v.y); o.z = f2bf(v.z); o.w = f2bf(v.w);
  *(ushort4*)(xb + i) = o;
}

// ------- convert W[h][c][d] -> Wt[w][n=h*64+d][c] bf16 (B^T layout) -------
__global__ __launch_bounds__(256) void cvt_w_kernel(const float* __restrict__ Wq,
                                                    const float* __restrict__ Wk,
                                                    const float* __restrict__ Wv,
                                                    u16* __restrict__ Wt) {
  __shared__ float tile[64][65];
  int w = blockIdx.z, h = blockIdx.y;
  int c0 = blockIdx.x * 64;
  const float* W = ((w == 0) ? Wq : (w == 1) ? Wk : Wv) + (size_t)h * CEMB * HS;
  int tid = threadIdx.x;
  int r = tid >> 4;
  int d4 = (tid & 15) * 4;
#pragma unroll
  for (int p = 0; p < 4; ++p) {
    int row = p * 16 + r;
    float4 v = *(const float4*)(W + (size_t)(c0 + row) * HS + d4);
    tile[row][d4] = v.x; tile[row][d4 + 1] = v.y;
    tile[row][d4 + 2] = v.z; tile[row][d4 + 3] = v.w;
  }
  __syncthreads();
  u16* dst = Wt + ((size_t)w << 20);
#pragma unroll
  for (int p = 0; p < 4; ++p) {
    int d = p * 16 + r;
    ushort4 o;
    o.x = f2bf(tile[d4][d]);     o.y = f2bf(tile[d4 + 1][d]);
    o.z = f2bf(tile[d4 + 2][d]); o.w = f2bf(tile[d4 + 3][d]);
    *(ushort4*)(dst + (size_t)(h * 64 + d) * CEMB + c0 + d4) = o;
  }
}

// ---------------- projection GEMM: [4096x1024] x [1024x1024]^T ----------------
#define BM 128
#define BN 128
#define BK 64

__global__ __launch_bounds__(256, 2) void proj_gemm(const u16* __restrict__ xb,
                                                    const u16* __restrict__ Wt,
                                                    u16* __restrict__ Qb,
                                                    u16* __restrict__ Kb,
                                                    u16* __restrict__ Vb) {
  __shared__ u16 As[BM * BK];
  __shared__ u16 Bs[BN * BK];
  int z = blockIdx.z;
  const u16* Wz = Wt + (size_t)z * (1024 * 1024);
  u16* outp = (z == 0) ? Qb : (z == 1) ? Kb : Vb;
  int tile_m = blockIdx.x * BM;
  int tile_n = blockIdx.y * BN;
  int tid  = threadIdx.x;
  int lane = tid & 63;
  int wave = tid >> 6;
  int wr = wave >> 1, wc = wave & 1;
  int l15 = lane & 15, lg = lane >> 4;

  f32x4 acc[4][4] = {};

  for (int k0 = 0; k0 < CEMB; k0 += BK) {
#pragma unroll
    for (int j = 0; j < 4; ++j) {
      int off = j * 4096 + tid * 16;
      int row = off >> 7;
      int g   = (off >> 4) & 7;
      int col = ((g ^ (row & 7)) << 3);
      const u16* srcA = xb + (size_t)(tile_m + row) * CEMB + k0 + col;
      ASYNC_CP16(srcA, (char*)As + j * 4096 + wave * 1024);
      const u16* srcB = Wz + (size_t)(tile_n + row) * CEMB + k0 + col;
      ASYNC_CP16(srcB, (char*)Bs + j * 4096 + wave * 1024);
    }
    __syncthreads();

    bf16x8 af[2][4], bfr[2][4];
#pragma unroll
    for (int kk = 0; kk < 2; ++kk) {
#pragma unroll
      for (int m = 0; m < 4; ++m) {
        int row = wr * 64 + m * 16 + l15;
        int g   = kk * 4 + lg;
        af[kk][m] = *(const bf16x8*)(const void*)((const char*)As + row * 128 +
                                                  ((g ^ (row & 7)) << 4));
      }
#pragma unroll
      for (int n = 0; n < 4; ++n) {
        int row = wc * 64 + n * 16 + l15;
        int g   = kk * 4 + lg;
        bfr[kk][n] = *(const bf16x8*)(const void*)((const char*)Bs + row * 128 +
                                                   ((g ^ (row & 7)) << 4));
      }
    }
#pragma unroll
    for (int kk = 0; kk < 2; ++kk)
#pragma unroll
      for (int m = 0; m < 4; ++m)
#pragma unroll
        for (int n = 0; n < 4; ++n)
          acc[m][n] = __builtin_amdgcn_mfma_f32_16x16x32_bf16(af[kk][m], bfr[kk][n],
                                                              acc[m][n], 0, 0, 0);
    __syncthreads();
  }

#pragma unroll
  for (int m = 0; m < 4; ++m)
#pragma unroll
    for (int n = 0; n < 4; ++n)
#pragma unroll
      for (int i = 0; i < 4; ++i) {
        int row = tile_m + wr * 64 + m * 16 + lg * 4 + i;  // b*T + t
        int col = tile_n + wc * 64 + n * 16 + l15;         // h*64 + d
        int b = row >> 11, t = row & 2047;
        int h = col >> 6,  d = col & 63;
        outp[(size_t)((b << 4) + h) * (T_SEQ * HS) + (size_t)t * HS + d] =
            f2bf(acc[m][n][i]);
      }
}

// ---------------- V [bh][t][d] -> Vt [bh][d][t] ----------------
__global__ __launch_bounds__(256) void transpose_v_kernel(const u16* __restrict__ Vb,
                                                          u16* __restrict__ Vt) {
  __shared__ u16 tile[64][72];
  int bh = blockIdx.y;
  int t0 = blockIdx.x * 64;
  int tid = threadIdx.x;
  int r = tid >> 3, c8 = (tid & 7) * 8;
  const u16* src = Vb + ((size_t)bh * T_SEQ + t0) * HS;
#pragma unroll
  for (int p = 0; p < 2; ++p) {
    int rr = r + p * 32;
    bf16x8 v = ld8(src + rr * HS + c8);
#pragma unroll
    for (int j = 0; j < 8; ++j) tile[rr][c8 + j] = ((const u16*)&v)[j];
  }
  __syncthreads();
  u16* dst = Vt + (size_t)bh * HS * T_SEQ + t0;
#pragma unroll
  for (int p = 0; p < 2; ++p) {
    int d = r + p * 32;
    u16 tmp[8] __attribute__((aligned(16)));
#pragma unroll
    for (int j = 0; j < 8; ++j) tmp[j] = tile[c8 + j][d];
    *(bf16x8*)(void*)(dst + (size_t)d * T_SEQ + c8) = *(const bf16x8*)(const void*)tmp;
  }
}

// ---------------- causal flash attention v3: swapped QK^T, in-reg softmax ----
// 4 waves x 32 q-rows = 128 q-rows/block. KVBLK=64, 32x32x16 MFMA.
// Each lane owns ONE q-row (q = qw + (lane&31)); lane pair (l, l+32) holds the
// row's 64 P-values (32 each). Softmax: in-lane tree + one shfl_xor(32).
// P -> PV B-frags fully in-register via v_perm pack + shfl_xor(32) exchange.
__global__ __launch_bounds__(256, 2) void attn_kernel(const u16* __restrict__ Qb,
                                                      const u16* __restrict__ Kb,
                                                      const u16* __restrict__ Vt,
                                                      float* __restrict__ out) {
  __shared__ u16 Ks[2][4096];   // 2 x [64 kv][64 d]   (8 KB each, XOR-swizzled)
  __shared__ u16 Vs[2][4096];   // 2 x [64 d][64 kv]

  int bh = blockIdx.x;
  int y  = blockIdx.y;
  int qb = (y < 8) ? y : 23 - y;   // pair-balanced launch order
  int tid = threadIdx.x;
  int lane = tid & 63, wave = tid >> 6;
  int l31 = lane & 31, hi = lane >> 5;
  int qw = qb * 128 + wave * 32;

  const u16* Qh = Qb + (size_t)bh * T_SEQ * HS;
  const u16* Kh = Kb + (size_t)bh * T_SEQ * HS;
  const u16* Vh = Vt + (size_t)bh * HS * T_SEQ;

#define STAGE(tt, bb) do {                                                      \
    _Pragma("unroll")                                                           \
    for (int is = 0; is < 2; ++is) {                                            \
      int off_ = is * 4096 + tid * 16;                                          \
      int row_ = off_ >> 7;                                                     \
      int col_ = ((((off_ >> 4) & 7) ^ (row_ & 7)) << 3);                       \
      ASYNC_CP16(Kh + (size_t)((tt) * 64 + row_) * HS + col_,                   \
                 (char*)&Ks[bb][0] + is * 4096 + wave * 1024);                  \
      ASYNC_CP16(Vh + (size_t)row_ * T_SEQ + (tt) * 64 + col_,                  \
                 (char*)&Vs[bb][0] + is * 4096 + wave * 1024);                  \
    }                                                                           \
  } while (0)

  // Q B-frags: B[k=d][col=q]: lane holds Q[qw+l31][kk*16 + hi*8 .. +8)
  bf16x8 qf[4];
#pragma unroll
  for (int kk = 0; kk < 4; ++kk)
    qf[kk] = ld8(Qh + (size_t)(qw + l31) * HS + kk * 16 + hi * 8);

  f32x16 ot0 = {}, ot1 = {};        // O^T: d 0..31 / 32..63
  float mrow = -1e30f, lsum = 0.f;
  const float sc = 0.03125f * 1.44269504f;   // log2(e)/sqrt(C)

  int lastt = (qw + 31) >> 6;
  int maxT  = 2 * qb + 1;

  STAGE(0, 0);
  __syncthreads();

  for (int t = 0; t <= maxT; ++t) {
    int b = t & 1;
    if (t < maxT) STAGE(t + 1, b ^ 1);

    if (t <= lastt) {
      // ---- S^T = K_tile · Q^T  (two 32-kv sub-tiles) ----
      f32x16 st0 = {}, st1 = {};
#pragma unroll
      for (int kk = 0; kk < 4; ++kk) {
        int g = 2 * kk + hi;
        int sw = ((g ^ (l31 & 7)) << 4);
        bf16x8 kf0 = *(const bf16x8*)(const void*)((const char*)&Ks[b][0] +
                                                   l31 * 128 + sw);
        bf16x8 kf1 = *(const bf16x8*)(const void*)((const char*)&Ks[b][0] +
                                                   (32 + l31) * 128 + sw);
        st0 = __builtin_amdgcn_mfma_f32_32x32x16_bf16(kf0, qf[kk], st0, 0, 0, 0);
        st1 = __builtin_amdgcn_mfma_f32_32x32x16_bf16(kf1, qf[kk], st1, 0, 0, 0);
      }
      // ---- scale (log2 domain) + causal mask ----
#pragma unroll
      for (int r = 0; r < 16; ++r) { st0[r] *= sc; st1[r] *= sc; }
      if (t == lastt) {
        int qrel = qw + l31 - t * 64 - 4 * hi;
#pragma unroll
        for (int r = 0; r < 16; ++r) {
          int kr = (r & 3) + 8 * (r >> 2);
          if (kr > qrel)      st0[r] = -1e30f;
          if (kr + 32 > qrel) st1[r] = -1e30f;
        }
      }
      // ---- online softmax (per-lane scalar m, l) ----
      float pm0 = -1e30f, pm1 = -1e30f, pm2 = -1e30f, pm3 = -1e30f;
#pragma unroll
      for (int r = 0; r < 16; r += 4) {
        pm0 = fmaxf(pm0, fmaxf(st0[r],     st1[r]));
        pm1 = fmaxf(pm1, fmaxf(st0[r + 1], st1[r + 1]));
        pm2 = fmaxf(pm2, fmaxf(st0[r + 2], st1[r + 2]));
        pm3 = fmaxf(pm3, fmaxf(st0[r + 3], st1[r + 3]));
      }
      float vmax = fmaxf(fmaxf(pm0, pm1), fmaxf(pm2, pm3));
      vmax = fmaxf(vmax, __shfl_xor(vmax, 32));
      float mnew = fmaxf(mrow, vmax);
      float ps = exp2f(mrow - mnew);
      mrow = mnew;
      float s0 = 0.f, s1 = 0.f, s2 = 0.f, s3 = 0.f;
#pragma unroll
      for (int r = 0; r < 16; r += 4) {
        st0[r]     = exp2f(st0[r]     - mnew); st1[r]     = exp2f(st1[r]     - mnew);
        st0[r + 1] = exp2f(st0[r + 1] - mnew); st1[r + 1] = exp2f(st1[r + 1] - mnew);
        st0[r + 2] = exp2f(st0[r + 2] - mnew); st1[r + 2] = exp2f(st1[r + 2] - mnew);
        st0[r + 3] = exp2f(st0[r + 3] - mnew); st1[r + 3] = exp2f(st1[r + 3] - mnew);
        s0 += st0[r]     + st1[r];
        s1 += st0[r + 1] + st1[r + 1];
        s2 += st0[r + 2] + st1[r + 2];
        s3 += st0[r + 3] + st1[r + 3];
      }
      float rsum = (s0 + s1) + (s2 + s3);
      rsum += __shfl_xor(rsum, 32);
      lsum = lsum * ps + rsum;
#pragma unroll
      for (int r = 0; r < 16; ++r) { ot0[r] *= ps; ot1[r] *= ps; }

      // ---- P -> PV B-frags (in-register pack + lane-half exchange) ----
      bf16x8 pf[4];
#pragma unroll
      for (int kk = 0; kk < 4; ++kk) {
        int c = kk & 1;
        float e0, e1, e2, e3, e4, e5, e6, e7;
        if (kk < 2) {
          e0 = st0[8*c+0]; e1 = st0[8*c+1]; e2 = st0[8*c+2]; e3 = st0[8*c+3];
          e4 = st0[8*c+4]; e5 = st0[8*c+5]; e6 = st0[8*c+6]; e7 = st0[8*c+7];
        } else {
          e0 = st1[8*c+0]; e1 = st1[8*c+1]; e2 = st1[8*c+2]; e3 = st1[8*c+3];
          e4 = st1[8*c+4]; e5 = st1[8*c+5]; e6 = st1[8*c+6]; e7 = st1[8*c+7];
        }
        uint32_t A0 = pkbf(e0, e1), A1 = pkbf(e2, e3);
        uint32_t B0 = pkbf(e4, e5), B1 = pkbf(e6, e7);
        uint32_t X0 = hi ? A0 : B0, X1 = hi ? A1 : B1;
        uint32_t R0 = (uint32_t)__shfl_xor((int)X0, 32);
        uint32_t R1 = (uint32_t)__shfl_xor((int)X1, 32);
        union { uint32_t w[4]; bf16x8 v; } u;
        u.w[0] = hi ? R0 : A0;  u.w[1] = hi ? R1 : A1;
        u.w[2] = hi ? B0 : R0;  u.w[3] = hi ? B1 : R1;
        pf[kk] = u.v;
      }
      // ---- O^T += V^T · P^T ----
#pragma unroll
      for (int kk = 0; kk < 4; ++kk) {
        int g = 2 * kk + hi;
        int sw = ((g ^ (l31 & 7)) << 4);
        bf16x8 vf0 = *(const bf16x8*)(const void*)((const char*)&Vs[b][0] +
                                                   l31 * 128 + sw);
        bf16x8 vf1 = *(const bf16x8*)(const void*)((const char*)&Vs[b][0] +
                                                   (32 + l31) * 128 + sw);
        ot0 = __builtin_amdgcn_mfma_f32_32x32x16_bf16(vf0, pf[kk], ot0, 0, 0, 0);
        ot1 = __builtin_amdgcn_mfma_f32_32x32x16_bf16(vf1, pf[kk], ot1, 0, 0, 0);
      }
    }
    __syncthreads();
  }

  // ---- epilogue: lane owns q-row qw+l31, d-slices (r&3)+8*(r>>2)+4*hi (+32) ----
  int bb = bh >> 4, hh = bh & 15;
  int qrow = qw + l31;
  float inv = 1.0f / lsum;
  float* op = out + ((size_t)bb * T_SEQ + qrow) * CEMB + hh * HS + 4 * hi;
#pragma unroll
  for (int rq = 0; rq < 4; ++rq) {
    f32x4 v0, v1;
#pragma unroll
    for (int i = 0; i < 4; ++i) {
      v0[i] = ot0[4 * rq + i] * inv;
      v1[i] = ot1[4 * rq + i] * inv;
    }
    *(f32x4*)(void*)(op + 8 * rq)      = v0;
    *(f32x4*)(void*)(op + 32 + 8 * rq) = v1;
  }
#undef STAGE
}

extern "C" void kernel_launch(void* const* d_in, const int* in_sizes, int n_in,
                              void* d_out, int out_size, void* d_ws, size_t ws_size,
                              hipStream_t stream) {
  const float* x  = (const float*)d_in[0];
  const float* Wq = (const float*)d_in[1];
  const float* Wk = (const float*)d_in[2];
  const float* Wv = (const float*)d_in[3];
  float* out = (float*)d_out;
  char* ws = (char*)d_ws;

  u16* xb = (u16*)ws;                      // 8 MB  [4096][1024] bf16; reused as Vt
  u16* Wt = (u16*)(ws + (8u << 20));       // 6 MB  [3][1024][1024] bf16
  u16* Qb = (u16*)(ws + (14u << 20));      // 8 MB  [bh][t][d] bf16
  u16* Kb = (u16*)(ws + (22u << 20));      // 8 MB
  u16* Vb = (u16*)(ws + (30u << 20));      // 8 MB
  u16* Vt = xb;                            // xb dead after proj_gemm

  cvt_x_kernel<<<4096, 256, 0, stream>>>(x, xb);
  cvt_w_kernel<<<dim3(16, 16, 3), 256, 0, stream>>>(Wq, Wk, Wv, Wt);
  proj_gemm<<<dim3(32, 8, 3), 256, 0, stream>>>(xb, Wt, Qb, Kb, Vb);
  transpose_v_kernel<<<dim3(32, 32), 256, 0, stream>>>(Vb, Vt);
  attn_kernel<<<dim3(32, 16), 256, 0, stream>>>(Qb, Kb, Vt, out);
}